// Round 1
// baseline (9398.320 us; speedup 1.0000x reference)
//
#include <hip/hip_runtime.h>
#include <math.h>

#define DD 128

__device__ __forceinline__ void atomicMaxFloat(float* addr, float val) {
    if (val >= 0.f) atomicMax((int*)addr, __float_as_int(val));
    else            atomicMin((unsigned int*)addr, __float_as_uint(val));
}

// C[N][128] = X[N][128] @ W[128][128] + b ; optional relu on X load (layer-2 input)
template<bool RELU_IN>
__global__ __launch_bounds__(256) void gemm_xw(const float* __restrict__ X,
                                               const float* __restrict__ W,
                                               const float* __restrict__ b,
                                               float* __restrict__ C, int nrows)
{
    __shared__ __align__(16) float Xs[32][DD];
    const int block_row = blockIdx.x * 32;
    const int tid = threadIdx.x;

    // stage 32x128 X tile (1024 float4, 4 per thread)
    for (int i = tid; i < 1024; i += 256) {
        int r  = i >> 5;        // 32 float4 per row
        int c4 = i & 31;
        int row = block_row + r;
        float4 v = make_float4(0.f, 0.f, 0.f, 0.f);
        if (row < nrows) v = ((const float4*)X)[(size_t)row * 32 + c4];
        if (RELU_IN) {
            v.x = fmaxf(v.x, 0.f); v.y = fmaxf(v.y, 0.f);
            v.z = fmaxf(v.z, 0.f); v.w = fmaxf(v.w, 0.f);
        }
        *(float4*)&Xs[r][c4 * 4] = v;
    }
    __syncthreads();

    const int rg = tid >> 5;   // 0..7
    const int cg = tid & 31;   // 0..31
    const int r0 = rg * 4;
    const int c0 = cg * 4;

    float4 acc[4];
    #pragma unroll
    for (int r = 0; r < 4; ++r) acc[r] = make_float4(0.f, 0.f, 0.f, 0.f);

    for (int k = 0; k < DD; k += 4) {
        float4 w0 = *(const float4*)&W[(k + 0) * DD + c0];
        float4 w1 = *(const float4*)&W[(k + 1) * DD + c0];
        float4 w2 = *(const float4*)&W[(k + 2) * DD + c0];
        float4 w3 = *(const float4*)&W[(k + 3) * DD + c0];
        #pragma unroll
        for (int r = 0; r < 4; ++r) {
            float4 xv = *(const float4*)&Xs[r0 + r][k];
            acc[r].x = fmaf(xv.x, w0.x, fmaf(xv.y, w1.x, fmaf(xv.z, w2.x, fmaf(xv.w, w3.x, acc[r].x))));
            acc[r].y = fmaf(xv.x, w0.y, fmaf(xv.y, w1.y, fmaf(xv.z, w2.y, fmaf(xv.w, w3.y, acc[r].y))));
            acc[r].z = fmaf(xv.x, w0.z, fmaf(xv.y, w1.z, fmaf(xv.z, w2.z, fmaf(xv.w, w3.z, acc[r].z))));
            acc[r].w = fmaf(xv.x, w0.w, fmaf(xv.y, w1.w, fmaf(xv.z, w2.w, fmaf(xv.w, w3.w, acc[r].w))));
        }
    }

    float4 bv = *(const float4*)&b[c0];
    #pragma unroll
    for (int r = 0; r < 4; ++r) {
        int row = block_row + r0 + r;
        if (row < nrows) {
            float4 o = make_float4(acc[r].x + bv.x, acc[r].y + bv.y,
                                   acc[r].z + bv.z, acc[r].w + bv.w);
            *(float4*)&C[(size_t)row * DD + c0] = o;
        }
    }
}

// Wc = A(128x128) @ B(128x128); bc = bin(128) @ B.  grid=64 blocks x 256 thr, 2 rows/block.
__global__ __launch_bounds__(256) void combine_w(const float* __restrict__ A,
                                                 const float* __restrict__ bin,
                                                 const float* __restrict__ B,
                                                 float* __restrict__ Wc,
                                                 float* __restrict__ bc)
{
    const int tid = threadIdx.x;
    const int i = blockIdx.x * 2 + (tid >> 7);
    const int j = tid & 127;
    float sum = 0.f;
    for (int k = 0; k < DD; ++k) sum = fmaf(A[i * DD + k], B[k * DD + j], sum);
    Wc[i * DD + j] = sum;
    if (blockIdx.x == 0 && tid < DD) {
        float s2 = 0.f;
        for (int k = 0; k < DD; ++k) s2 = fmaf(bin[k], B[k * DD + j], s2);
        bc[j] = s2;
    }
}

// zero out[0:nd], m=-inf, denom=0
__global__ __launch_bounds__(256) void init_attn(float* __restrict__ out,
                                                 float* __restrict__ m,
                                                 float* __restrict__ denom,
                                                 int n, int nd)
{
    int i = blockIdx.x * 256 + threadIdx.x;
    if (i < nd) out[i] = 0.f;
    if (i < n) { m[i] = -__builtin_inff(); denom[i] = 0.f; }
}

// s[e] = leaky_relu(dot(QW[src], K[dst]) / sqrt(D)); atomic max into m[dst]. 16 lanes/edge.
__global__ __launch_bounds__(256) void edge_scores(const float* __restrict__ QW,
                                                   const float* __restrict__ K,
                                                   const int* __restrict__ src,
                                                   const int* __restrict__ dst,
                                                   float* __restrict__ sbuf,
                                                   float* __restrict__ m, int nE)
{
    int t = blockIdx.x * 256 + threadIdx.x;
    int e = t >> 4;
    int li = t & 15;
    if (e >= nE) return;
    int s = src[e], d = dst[e];
    const float4* q4 = (const float4*)(QW + (size_t)s * DD);
    const float4* k4 = (const float4*)(K + (size_t)d * DD);
    float4 a0 = q4[li * 2], a1 = q4[li * 2 + 1];
    float4 b0 = k4[li * 2], b1 = k4[li * 2 + 1];
    float dot = a0.x * b0.x + a0.y * b0.y + a0.z * b0.z + a0.w * b0.w
              + a1.x * b1.x + a1.y * b1.y + a1.z * b1.z + a1.w * b1.w;
    dot += __shfl_xor(dot, 1);
    dot += __shfl_xor(dot, 2);
    dot += __shfl_xor(dot, 4);
    dot += __shfl_xor(dot, 8);
    if (li == 0) {
        float sc = dot * 0.08838834764831845f;   // 1/sqrt(128)
        sc = sc > 0.f ? sc : 0.01f * sc;         // leaky_relu
        sbuf[e] = sc;
        atomicMaxFloat(&m[d], sc);
    }
}

// e = exp(s - m[dst]); denom[dst] += e
__global__ __launch_bounds__(256) void edge_expsum(const float* __restrict__ mbuf,
                                                   const int* __restrict__ dst,
                                                   float* __restrict__ sbuf,
                                                   float* __restrict__ denom, int nE)
{
    int e = blockIdx.x * 256 + threadIdx.x;
    if (e >= nE) return;
    int d = dst[e];
    float ev = __expf(sbuf[e] - mbuf[d]);
    sbuf[e] = ev;
    atomicAdd(&denom[d], ev);
}

// out[dst] += (e/denom[dst]) * V[src] ; 16 lanes/edge, 8 floats/lane
__global__ __launch_bounds__(256) void edge_scatter(const float* __restrict__ V,
                                                    const int* __restrict__ src,
                                                    const int* __restrict__ dst,
                                                    const float* __restrict__ sbuf,
                                                    const float* __restrict__ denom,
                                                    float* __restrict__ out, int nE)
{
    int t = blockIdx.x * 256 + threadIdx.x;
    int e = t >> 4;
    int li = t & 15;
    if (e >= nE) return;
    int s = src[e], d = dst[e];
    float alpha = sbuf[e] / denom[d];
    const float4* v4 = (const float4*)(V + (size_t)s * DD);
    float4 a = v4[li * 2], b = v4[li * 2 + 1];
    float* o = out + (size_t)d * DD + li * 8;
    atomicAdd(o + 0, alpha * a.x);
    atomicAdd(o + 1, alpha * a.y);
    atomicAdd(o + 2, alpha * a.z);
    atomicAdd(o + 3, alpha * a.w);
    atomicAdd(o + 4, alpha * b.x);
    atomicAdd(o + 5, alpha * b.y);
    atomicAdd(o + 6, alpha * b.z);
    atomicAdd(o + 7, alpha * b.w);
}

extern "C" void kernel_launch(void* const* d_in, const int* in_sizes, int n_in,
                              void* d_out, int out_size, void* d_ws, size_t ws_size,
                              hipStream_t stream)
{
    const float* x_a   = (const float*)d_in[0];
    const float* x_b   = (const float*)d_in[1];
    const int*   ei_ab = (const int*)d_in[2];
    const int*   ei_ba = (const int*)d_in[3];
    const float* qkv_w = (const float*)d_in[4];
    const float* qkv_b = (const float*)d_in[5];
    const float* edge_W= (const float*)d_in[6];
    float* out = (float*)d_out;

    const int N = in_sizes[0] / DD;    // 50000
    const int E = in_sizes[2] / 2;     // 600000

    float* ws = (float*)d_ws;
    float* F0  = ws;                       // qW  [N*D]
    float* F1  = F0 + (size_t)N * DD;      // k   [N*D]
    float* F2  = F1 + (size_t)N * DD;      // v   [N*D]
    float* HA  = F2 + (size_t)N * DD;      // layer-1 out a
    float* HB  = HA + (size_t)N * DD;      // layer-1 out b
    float* SB  = HB + (size_t)N * DD;      // per-edge scalar [E]
    float* M   = SB + E;                   // per-dst max [N]
    float* DEN = M + N;                    // per-dst denom [N]
    float* WC  = DEN + N;                  // combined weight [D*D]
    float* BC  = WC + DD * DD;             // combined bias [D]

    auto w  = [&](int L, int T, int i) { return qkv_w + (((size_t)L * 2 + T) * 3 + i) * DD * DD; };
    auto bb = [&](int L, int T, int i) { return qkv_b + (((size_t)L * 2 + T) * 3 + i) * DD; };
    auto eW = [&](int L, int et)       { return edge_W + ((size_t)L * 2 + et) * DD * DD; };

    const int gemm_grid  = (N + 31) / 32;
    const int esc_grid   = (E * 16 + 255) / 256;
    const int epb_grid   = (E + 255) / 256;
    const int init_grid  = (N * DD + 255) / 256;

    auto attend = [&](const float* Xsrc, const float* Xdst, bool relu_in,
                      const float* wq, const float* bq,
                      const float* wk, const float* bk,
                      const float* wv, const float* bv,
                      const float* We, const int* ei, float* outbuf) {
        combine_w<<<64, 256, 0, stream>>>(wq, bq, We, WC, BC);
        if (relu_in) {
            gemm_xw<true ><<<gemm_grid, 256, 0, stream>>>(Xsrc, WC, BC, F0, N);
            gemm_xw<true ><<<gemm_grid, 256, 0, stream>>>(Xdst, wk, bk, F1, N);
            gemm_xw<true ><<<gemm_grid, 256, 0, stream>>>(Xsrc, wv, bv, F2, N);
        } else {
            gemm_xw<false><<<gemm_grid, 256, 0, stream>>>(Xsrc, WC, BC, F0, N);
            gemm_xw<false><<<gemm_grid, 256, 0, stream>>>(Xdst, wk, bk, F1, N);
            gemm_xw<false><<<gemm_grid, 256, 0, stream>>>(Xsrc, wv, bv, F2, N);
        }
        init_attn<<<init_grid, 256, 0, stream>>>(outbuf, M, DEN, N, N * DD);
        const int* srcp = ei;
        const int* dstp = ei + E;
        edge_scores <<<esc_grid, 256, 0, stream>>>(F0, F1, srcp, dstp, SB, M, E);
        edge_expsum <<<epb_grid, 256, 0, stream>>>(M, dstp, SB, DEN, E);
        edge_scatter<<<esc_grid, 256, 0, stream>>>(F2, srcp, dstp, SB, DEN, outbuf, E);
    };

    // ---- layer 1 (inputs x_a, x_b; outputs HA, HB in ws) ----
    // a->b : q/v from 'a', k from 'b', edge type 0, dst in b
    attend(x_a, x_b, false, w(0,0,0), bb(0,0,0), w(0,1,1), bb(0,1,1),
           w(0,0,2), bb(0,0,2), eW(0,0), ei_ab, HB);
    // b->a : q/v from 'b', k from 'a', edge type 1, dst in a
    attend(x_b, x_a, false, w(0,1,0), bb(0,1,0), w(0,0,1), bb(0,0,1),
           w(0,1,2), bb(0,1,2), eW(0,1), ei_ba, HA);

    // ---- layer 2 (relu fused into GEMM input loads; outputs to d_out) ----
    float* o_a = out;
    float* o_b = out + (size_t)N * DD;
    attend(HA, HB, true, w(1,0,0), bb(1,0,0), w(1,1,1), bb(1,1,1),
           w(1,0,2), bb(1,0,2), eW(1,0), ei_ab, o_b);
    attend(HB, HA, true, w(1,1,0), bb(1,1,0), w(1,0,1), bb(1,0,1),
           w(1,1,2), bb(1,1,2), eW(1,1), ei_ba, o_a);
}

// Round 2
// 1093.102 us; speedup vs baseline: 8.5978x; 8.5978x over previous
//
#include <hip/hip_runtime.h>
#include <math.h>

#define DD 128

// ============================ GEMM ============================
// C[N][128] = X[N][128] @ W[128][128] + b ; optional relu on X load (layer-2 input)
template<bool RELU_IN>
__global__ __launch_bounds__(256) void gemm_xw(const float* __restrict__ X,
                                               const float* __restrict__ W,
                                               const float* __restrict__ b,
                                               float* __restrict__ C, int nrows)
{
    __shared__ __align__(16) float Xs[32][DD];
    const int block_row = blockIdx.x * 32;
    const int tid = threadIdx.x;

    for (int i = tid; i < 1024; i += 256) {
        int r  = i >> 5;
        int c4 = i & 31;
        int row = block_row + r;
        float4 v = make_float4(0.f, 0.f, 0.f, 0.f);
        if (row < nrows) v = ((const float4*)X)[(size_t)row * 32 + c4];
        if (RELU_IN) {
            v.x = fmaxf(v.x, 0.f); v.y = fmaxf(v.y, 0.f);
            v.z = fmaxf(v.z, 0.f); v.w = fmaxf(v.w, 0.f);
        }
        *(float4*)&Xs[r][c4 * 4] = v;
    }
    __syncthreads();

    const int rg = tid >> 5;
    const int cg = tid & 31;
    const int r0 = rg * 4;
    const int c0 = cg * 4;

    float4 acc[4];
    #pragma unroll
    for (int r = 0; r < 4; ++r) acc[r] = make_float4(0.f, 0.f, 0.f, 0.f);

    for (int k = 0; k < DD; k += 4) {
        float4 w0 = *(const float4*)&W[(k + 0) * DD + c0];
        float4 w1 = *(const float4*)&W[(k + 1) * DD + c0];
        float4 w2 = *(const float4*)&W[(k + 2) * DD + c0];
        float4 w3 = *(const float4*)&W[(k + 3) * DD + c0];
        #pragma unroll
        for (int r = 0; r < 4; ++r) {
            float4 xv = *(const float4*)&Xs[r0 + r][k];
            acc[r].x = fmaf(xv.x, w0.x, fmaf(xv.y, w1.x, fmaf(xv.z, w2.x, fmaf(xv.w, w3.x, acc[r].x))));
            acc[r].y = fmaf(xv.x, w0.y, fmaf(xv.y, w1.y, fmaf(xv.z, w2.y, fmaf(xv.w, w3.y, acc[r].y))));
            acc[r].z = fmaf(xv.x, w0.z, fmaf(xv.y, w1.z, fmaf(xv.z, w2.z, fmaf(xv.w, w3.z, acc[r].z))));
            acc[r].w = fmaf(xv.x, w0.w, fmaf(xv.y, w1.w, fmaf(xv.z, w2.w, fmaf(xv.w, w3.w, acc[r].w))));
        }
    }

    float4 bv = *(const float4*)&b[c0];
    #pragma unroll
    for (int r = 0; r < 4; ++r) {
        int row = block_row + r0 + r;
        if (row < nrows) {
            float4 o = make_float4(acc[r].x + bv.x, acc[r].y + bv.y,
                                   acc[r].z + bv.z, acc[r].w + bv.w);
            *(float4*)&C[(size_t)row * DD + c0] = o;
        }
    }
}

// Wc = A(128x128) @ B(128x128); bc = bin(128) @ B.
__global__ __launch_bounds__(256) void combine_w(const float* __restrict__ A,
                                                 const float* __restrict__ bin,
                                                 const float* __restrict__ B,
                                                 float* __restrict__ Wc,
                                                 float* __restrict__ bc)
{
    const int tid = threadIdx.x;
    const int i = blockIdx.x * 2 + (tid >> 7);
    const int j = tid & 127;
    float sum = 0.f;
    for (int k = 0; k < DD; ++k) sum = fmaf(A[i * DD + k], B[k * DD + j], sum);
    Wc[i * DD + j] = sum;
    if (blockIdx.x == 0 && tid < DD) {
        float s2 = 0.f;
        for (int k = 0; k < DD; ++k) s2 = fmaf(bin[k], B[k * DD + j], s2);
        bc[j] = s2;
    }
}

// ============================ CSR build ============================
__global__ __launch_bounds__(256) void zero_ints(int* __restrict__ p, int n)
{
    int i = blockIdx.x * 256 + threadIdx.x;
    if (i < n) p[i] = 0;
}

__global__ __launch_bounds__(256) void count_deg(const int* __restrict__ dab,
                                                 const int* __restrict__ dba,
                                                 int* __restrict__ degab,
                                                 int* __restrict__ degba, int nE)
{
    int e = blockIdx.x * 256 + threadIdx.x;
    if (e < nE) {
        atomicAdd(&degab[dab[e]], 1);
        atomicAdd(&degba[dba[e]], 1);
    }
}

// one block per edge type; deg becomes cursor (exclusive prefix written in place)
__global__ __launch_bounds__(1024) void scan_deg(int* __restrict__ deg,
                                                 int* __restrict__ offs, int n)
{
    __shared__ int tmp[1024];
    __shared__ int carry_s;
    int* d = deg + (size_t)blockIdx.x * n;
    int* o = offs + (size_t)blockIdx.x * (n + 1);
    if (threadIdx.x == 0) carry_s = 0;
    __syncthreads();
    for (int base = 0; base < n; base += 1024) {
        int i = base + threadIdx.x;
        int v = (i < n) ? d[i] : 0;
        tmp[threadIdx.x] = v;
        __syncthreads();
        for (int off = 1; off < 1024; off <<= 1) {
            int t = (threadIdx.x >= (unsigned)off) ? tmp[threadIdx.x - off] : 0;
            __syncthreads();
            tmp[threadIdx.x] += t;
            __syncthreads();
        }
        int excl = carry_s + tmp[threadIdx.x] - v;
        if (i < n) { o[i] = excl; d[i] = excl; }   // d[] is now the fill cursor
        int total = tmp[1023];
        __syncthreads();
        if (threadIdx.x == 0) carry_s += total;
        __syncthreads();
    }
    if (threadIdx.x == 0) o[n] = carry_s;
}

__global__ __launch_bounds__(256) void fill_csr(const int* __restrict__ sab,
                                                const int* __restrict__ dab,
                                                const int* __restrict__ sba,
                                                const int* __restrict__ dba,
                                                int* __restrict__ curab,
                                                int* __restrict__ curba,
                                                int* __restrict__ colab,
                                                int* __restrict__ colba, int nE)
{
    int e = blockIdx.x * 256 + threadIdx.x;
    if (e < nE) {
        int p = atomicAdd(&curab[dab[e]], 1);
        colab[p] = sab[e];
        int q = atomicAdd(&curba[dba[e]], 1);
        colba[q] = sba[e];
    }
}

// ============================ fused attention (gather, no atomics) ============================
// one wave (64 lanes) per dst node: K[dst] in regs, loop incoming edges with
// online softmax, gather QW[src]/V[src] rows (512B coalesced), single write.
__global__ __launch_bounds__(256) void attn_gather(const float* __restrict__ QW,
                                                   const float* __restrict__ K,
                                                   const float* __restrict__ V,
                                                   const int* __restrict__ offs,
                                                   const int* __restrict__ col,
                                                   float* __restrict__ out, int n)
{
    int wid  = (blockIdx.x * 256 + threadIdx.x) >> 6;
    int lane = threadIdx.x & 63;
    if (wid >= n) return;

    int beg = offs[wid], end = offs[wid + 1];
    float2 kv = ((const float2*)(K + (size_t)wid * DD))[lane];

    float m = -__builtin_inff();
    float den = 0.f;
    float2 acc = make_float2(0.f, 0.f);

    for (int p = beg; p < end; ++p) {
        int s = col[p];
        float2 q = ((const float2*)(QW + (size_t)s * DD))[lane];
        float part = q.x * kv.x + q.y * kv.y;
        part += __shfl_xor(part, 1);
        part += __shfl_xor(part, 2);
        part += __shfl_xor(part, 4);
        part += __shfl_xor(part, 8);
        part += __shfl_xor(part, 16);
        part += __shfl_xor(part, 32);
        float sc = part * 0.08838834764831845f;      // 1/sqrt(128)
        sc = sc > 0.f ? sc : 0.01f * sc;             // leaky_relu
        float nm = fmaxf(m, sc);
        float f  = __expf(m - nm);                   // first iter: exp(-inf)=0
        float pe = __expf(sc - nm);
        float2 v = ((const float2*)(V + (size_t)s * DD))[lane];
        den   = den * f + pe;
        acc.x = acc.x * f + pe * v.x;
        acc.y = acc.y * f + pe * v.y;
        m = nm;
    }

    float inv = den > 0.f ? 1.f / den : 0.f;         // deg-0 dst -> zeros (matches ref)
    ((float2*)(out + (size_t)wid * DD))[lane] = make_float2(acc.x * inv, acc.y * inv);
}

// ============================ host ============================
extern "C" void kernel_launch(void* const* d_in, const int* in_sizes, int n_in,
                              void* d_out, int out_size, void* d_ws, size_t ws_size,
                              hipStream_t stream)
{
    const float* x_a    = (const float*)d_in[0];
    const float* x_b    = (const float*)d_in[1];
    const int*   ei_ab  = (const int*)d_in[2];
    const int*   ei_ba  = (const int*)d_in[3];
    const float* qkv_w  = (const float*)d_in[4];
    const float* qkv_b  = (const float*)d_in[5];
    const float* edge_W = (const float*)d_in[6];
    float* out = (float*)d_out;

    const int N = in_sizes[0] / DD;    // 50000
    const int E = in_sizes[2] / 2;     // 600000

    float* ws = (float*)d_ws;
    float* F0 = ws;                        // qW   [N*D]
    float* F1 = F0 + (size_t)N * DD;       // k    [N*D]
    float* F2 = F1 + (size_t)N * DD;       // v    [N*D]
    float* HA = F2 + (size_t)N * DD;       // layer-1 out a
    float* HB = HA + (size_t)N * DD;       // layer-1 out b
    float* WC = HB + (size_t)N * DD;       // combined weight [D*D]
    float* BC = WC + DD * DD;              // combined bias   [D]
    int* ip      = (int*)(BC + DD);
    int* deg2    = ip;                     // [2*N]  (becomes cursor after scan)
    int* offs2   = deg2 + 2 * (size_t)N;   // [2*(N+1)]
    int* col_ab  = offs2 + 2 * ((size_t)N + 1); // [E]
    int* col_ba  = col_ab + E;             // [E]

    auto w  = [&](int L, int T, int i) { return qkv_w + (((size_t)L * 2 + T) * 3 + i) * DD * DD; };
    auto bb = [&](int L, int T, int i) { return qkv_b + (((size_t)L * 2 + T) * 3 + i) * DD; };
    auto eW = [&](int L, int et)       { return edge_W + ((size_t)L * 2 + et) * DD * DD; };

    const int gemm_grid = (N + 31) / 32;
    const int e_grid    = (E + 255) / 256;

    // ---- build CSR for both edge types (reused by both layers) ----
    const int* s_ab = ei_ab;       const int* d_ab = ei_ab + E;
    const int* s_ba = ei_ba;       const int* d_ba = ei_ba + E;
    zero_ints<<<(2 * N + 255) / 256, 256, 0, stream>>>(deg2, 2 * N);
    count_deg<<<e_grid, 256, 0, stream>>>(d_ab, d_ba, deg2, deg2 + N, E);
    scan_deg<<<2, 1024, 0, stream>>>(deg2, offs2, N);
    fill_csr<<<e_grid, 256, 0, stream>>>(s_ab, d_ab, s_ba, d_ba,
                                         deg2, deg2 + N, col_ab, col_ba, E);
    const int* offs_ab = offs2;
    const int* offs_ba = offs2 + (N + 1);

    const int ag_grid = (N + 3) / 4;   // 4 waves per block

    auto attend = [&](const float* Xsrc, const float* Xdst, bool relu_in,
                      const float* wq, const float* bq,
                      const float* wk, const float* bk,
                      const float* wv, const float* bv,
                      const float* We, const int* offs, const int* col,
                      float* outbuf) {
        combine_w<<<64, 256, 0, stream>>>(wq, bq, We, WC, BC);
        if (relu_in) {
            gemm_xw<true ><<<gemm_grid, 256, 0, stream>>>(Xsrc, WC, BC, F0, N);
            gemm_xw<true ><<<gemm_grid, 256, 0, stream>>>(Xdst, wk, bk, F1, N);
            gemm_xw<true ><<<gemm_grid, 256, 0, stream>>>(Xsrc, wv, bv, F2, N);
        } else {
            gemm_xw<false><<<gemm_grid, 256, 0, stream>>>(Xsrc, WC, BC, F0, N);
            gemm_xw<false><<<gemm_grid, 256, 0, stream>>>(Xdst, wk, bk, F1, N);
            gemm_xw<false><<<gemm_grid, 256, 0, stream>>>(Xsrc, wv, bv, F2, N);
        }
        attn_gather<<<ag_grid, 256, 0, stream>>>(F0, F1, F2, offs, col, outbuf, N);
    };

    // ---- layer 1 ----
    attend(x_a, x_b, false, w(0,0,0), bb(0,0,0), w(0,1,1), bb(0,1,1),
           w(0,0,2), bb(0,0,2), eW(0,0), offs_ab, col_ab, HB);
    attend(x_b, x_a, false, w(0,1,0), bb(0,1,0), w(0,0,1), bb(0,0,1),
           w(0,1,2), bb(0,1,2), eW(0,1), offs_ba, col_ba, HA);

    // ---- layer 2 (relu fused into GEMM input loads) ----
    float* o_a = out;
    float* o_b = out + (size_t)N * DD;
    attend(HA, HB, true, w(1,0,0), bb(1,0,0), w(1,1,1), bb(1,1,1),
           w(1,0,2), bb(1,0,2), eW(1,0), offs_ab, col_ab, o_b);
    attend(HB, HA, true, w(1,1,0), bb(1,1,0), w(1,0,1), bb(1,0,1),
           w(1,1,2), bb(1,1,2), eW(1,1), offs_ba, col_ba, o_a);
}

// Round 3
// 802.597 us; speedup vs baseline: 11.7099x; 1.3620x over previous
//
#include <hip/hip_runtime.h>
#include <math.h>

#define DD 128

typedef __attribute__((ext_vector_type(8))) short bf16x8;  // 8 bf16 (4 VGPR)
typedef __attribute__((ext_vector_type(4))) float f32x4;   // 4 fp32 acc

__device__ __forceinline__ ushort f2bf(float f) {
    union { float f; unsigned u; } v; v.f = f;
    unsigned r = v.u + 0x7fff + ((v.u >> 16) & 1);   // RNE
    return (ushort)(r >> 16);
}

// ==================== weight prep (once per launch) ====================
// WC[z] = wq(L,t,0) @ eW(L,t)  (fp32, 128x128); BCq[z] = bq @ eW
__global__ __launch_bounds__(256) void combine_all(const float* __restrict__ qkv_w,
                                                   const float* __restrict__ qkv_b,
                                                   const float* __restrict__ edge_W,
                                                   float* __restrict__ WC,
                                                   float* __restrict__ BCq)
{
    const int z = blockIdx.y;          // (L<<1)|t
    const int L = z >> 1, t = z & 1;
    const float* wq = qkv_w + (((size_t)L * 2 + t) * 3 + 0) * DD * DD;
    const float* bq = qkv_b + (((size_t)L * 2 + t) * 3 + 0) * DD;
    const float* We = edge_W + ((size_t)L * 2 + t) * DD * DD;
    float* Wz = WC + (size_t)z * DD * DD;
    float* Bz = BCq + (size_t)z * DD;

    const int tid = threadIdx.x;
    const int i = blockIdx.x * 2 + (tid >> 7);
    const int j = tid & 127;
    float sum = 0.f;
    for (int k = 0; k < DD; ++k) sum = fmaf(wq[i * DD + k], We[k * DD + j], sum);
    Wz[i * DD + j] = sum;
    if (blockIdx.x == 0 && tid < DD) {
        float s2 = 0.f;
        for (int k = 0; k < DD; ++k) s2 = fmaf(bq[k], We[k * DD + j], s2);
        Bz[j] = s2;
    }
}

// Pack per z: B-matrix [3 colblocks: q(Wc) | v(wv) | k(wk)] x [K=128] into
// MFMA-fragment-linear bf16 chunks: ci=((cb*8+ct)*4+ks)*64+l, chunk = 8 bf16:
// W3[k0+j][c3], k0=ks*32+(l>>4)*8, c3=cb*128+ct*16+(l&15).  Plus bias3[384].
__global__ __launch_bounds__(256) void pack_all(const float* __restrict__ qkv_w,
                                                const float* __restrict__ qkv_b,
                                                const float* __restrict__ WC,
                                                const float* __restrict__ BCq,
                                                ushort* __restrict__ W3P,
                                                float* __restrict__ B3)
{
    const int z = blockIdx.y;
    const int L = z >> 1, t = z & 1;
    const int ci = blockIdx.x * 256 + threadIdx.x;     // 0..6143
    const int cb = ci >> 11;
    const int ct = (ci >> 8) & 7;
    const int ks = (ci >> 6) & 3;
    const int l  = ci & 63;
    const int c3 = cb * 128 + ct * 16 + (l & 15);
    const int k0 = ks * 32 + (l >> 4) * 8;

    const float* wv = qkv_w + (((size_t)L * 2 + t) * 3 + 2) * DD * DD;
    const float* wk = qkv_w + (((size_t)L * 2 + (t ^ 1)) * 3 + 1) * DD * DD;
    const float* src;
    int cc;
    if (c3 < 128)      { src = WC + (size_t)z * DD * DD; cc = c3; }
    else if (c3 < 256) { src = wv; cc = c3 - 128; }
    else               { src = wk; cc = c3 - 256; }

    ushort h[8];
    #pragma unroll
    for (int j = 0; j < 8; ++j) h[j] = f2bf(src[(size_t)(k0 + j) * DD + cc]);
    ushort* dst = W3P + (size_t)z * 6144 * 8 + (size_t)ci * 8;
    #pragma unroll
    for (int j = 0; j < 8; ++j) dst[j] = h[j];

    if (ci < 384) {
        float bv;
        if (ci < 128)      bv = BCq[(size_t)z * DD + ci];
        else if (ci < 256) bv = qkv_b[(((size_t)L * 2 + t) * 3 + 2) * DD + (ci - 128)];
        else               bv = qkv_b[(((size_t)L * 2 + (t ^ 1)) * 3 + 1) * DD + (ci - 256)];
        B3[(size_t)z * 384 + ci] = bv;
    }
}

// ==================== fused MFMA GEMM ====================
// grid (ceil(N/64), 3): y=0 -> q=Xsrc@Wc, y=1 -> v=Xsrc@wv, y=2 -> k=Xdst@wk.
// out buffer y at outbase + y*N*128.  64 rows/block, 128 cols, K=128.
template<bool RELU_IN>
__global__ __launch_bounds__(256) void gemm_mfma(const float* __restrict__ Xsrc,
                                                 const float* __restrict__ Xdst,
                                                 const ushort* __restrict__ Bp,   // z-block, 3*16384
                                                 const float* __restrict__ bias,  // [384]
                                                 float* __restrict__ outbase,
                                                 int N)
{
    const int by = blockIdx.y;
    const float* X = (by == 2) ? Xdst : Xsrc;
    const ushort* Bz = Bp + (size_t)by * 16384;
    const float* bz = bias + by * 128;
    float* out = outbase + (size_t)by * N * DD;

    __shared__ ushort As[1024 * 8];   // 16 KB, frag-linear
    __shared__ ushort Bs[2048 * 8];   // 32 KB, frag-linear

    const int tid  = threadIdx.x;
    const int row0 = blockIdx.x * 64;

    // stage B: straight linear 16B copy
    #pragma unroll
    for (int i = 0; i < 8; ++i) {
        int c = tid + i * 256;
        *(float4*)&Bs[(size_t)c * 8] = ((const float4*)Bz)[c];
    }

    // stage A: thread t -> row=t>>2, 4 k8-chunks; convert f32->bf16, frag-linear
    {
        const int r = tid >> 2;
        const int q = tid & 3;
        const int grow = row0 + r;
        const bool ok = grow < N;
        const float* xr = X + (size_t)grow * DD;
        #pragma unroll
        for (int i = 0; i < 4; ++i) {
            const int k8 = q + i * 4;        // 0..15
            const int k  = k8 * 8;
            float4 v0 = make_float4(0.f,0.f,0.f,0.f), v1 = v0;
            if (ok) {
                v0 = *(const float4*)&xr[k];
                v1 = *(const float4*)&xr[k + 4];
                if (RELU_IN) {
                    v0.x=fmaxf(v0.x,0.f); v0.y=fmaxf(v0.y,0.f); v0.z=fmaxf(v0.z,0.f); v0.w=fmaxf(v0.w,0.f);
                    v1.x=fmaxf(v1.x,0.f); v1.y=fmaxf(v1.y,0.f); v1.z=fmaxf(v1.z,0.f); v1.w=fmaxf(v1.w,0.f);
                }
            }
            bf16x8 h;
            h[0]=(short)f2bf(v0.x); h[1]=(short)f2bf(v0.y); h[2]=(short)f2bf(v0.z); h[3]=(short)f2bf(v0.w);
            h[4]=(short)f2bf(v1.x); h[5]=(short)f2bf(v1.y); h[6]=(short)f2bf(v1.z); h[7]=(short)f2bf(v1.w);
            const int ks = k >> 5;
            const int l  = (r & 15) + 16 * (k8 & 3);
            const int c  = (r >> 4) * 256 + ks * 64 + l;
            *(bf16x8*)&As[(size_t)c * 8] = h;
        }
    }
    __syncthreads();

    const int wave = tid >> 6;
    const int lane = tid & 63;

    bf16x8 a[4];
    #pragma unroll
    for (int ks = 0; ks < 4; ++ks)
        a[ks] = *(const bf16x8*)&As[(size_t)(wave * 256 + ks * 64 + lane) * 8];

    f32x4 acc[8];
    #pragma unroll
    for (int ct = 0; ct < 8; ++ct) {
        acc[ct] = (f32x4){0.f, 0.f, 0.f, 0.f};
        #pragma unroll
        for (int ks = 0; ks < 4; ++ks) {
            bf16x8 b = *(const bf16x8*)&Bs[(size_t)((ct * 4 + ks) * 64 + lane) * 8];
            acc[ct] = __builtin_amdgcn_mfma_f32_16x16x32_bf16(a[ks], b, acc[ct], 0, 0, 0);
        }
    }

    // store: C/D map col=lane&15, row=(lane>>4)*4+reg
    const int rbase = row0 + wave * 16 + (lane >> 4) * 4;
    #pragma unroll
    for (int ct = 0; ct < 8; ++ct) {
        const int col = ct * 16 + (lane & 15);
        const float bv = bz[col];
        float* ob = out + col;
        #pragma unroll
        for (int j = 0; j < 4; ++j) {
            const int rr = rbase + j;
            if (rr < N) ob[(size_t)rr * DD] = acc[ct][j] + bv;
        }
    }
}

// ==================== CSR build ====================
__global__ __launch_bounds__(256) void zero_ints(int* __restrict__ p, int n)
{
    int i = blockIdx.x * 256 + threadIdx.x;
    if (i < n) p[i] = 0;
}

__global__ __launch_bounds__(256) void count_deg(const int* __restrict__ dab,
                                                 const int* __restrict__ dba,
                                                 int* __restrict__ degab,
                                                 int* __restrict__ degba, int nE)
{
    int e = blockIdx.x * 256 + threadIdx.x;
    if (e < nE) {
        atomicAdd(&degab[dab[e]], 1);
        atomicAdd(&degba[dba[e]], 1);
    }
}

__global__ __launch_bounds__(1024) void scan_deg(int* __restrict__ deg,
                                                 int* __restrict__ offs, int n)
{
    __shared__ int tmp[1024];
    __shared__ int carry_s;
    int* d = deg + (size_t)blockIdx.x * n;
    int* o = offs + (size_t)blockIdx.x * (n + 1);
    if (threadIdx.x == 0) carry_s = 0;
    __syncthreads();
    for (int base = 0; base < n; base += 1024) {
        int i = base + threadIdx.x;
        int v = (i < n) ? d[i] : 0;
        tmp[threadIdx.x] = v;
        __syncthreads();
        for (int off = 1; off < 1024; off <<= 1) {
            int t = (threadIdx.x >= (unsigned)off) ? tmp[threadIdx.x - off] : 0;
            __syncthreads();
            tmp[threadIdx.x] += t;
            __syncthreads();
        }
        int excl = carry_s + tmp[threadIdx.x] - v;
        if (i < n) { o[i] = excl; d[i] = excl; }
        int total = tmp[1023];
        __syncthreads();
        if (threadIdx.x == 0) carry_s += total;
        __syncthreads();
    }
    if (threadIdx.x == 0) o[n] = carry_s;
}

__global__ __launch_bounds__(256) void fill_csr(const int* __restrict__ sab,
                                                const int* __restrict__ dab,
                                                const int* __restrict__ sba,
                                                const int* __restrict__ dba,
                                                int* __restrict__ curab,
                                                int* __restrict__ curba,
                                                int* __restrict__ colab,
                                                int* __restrict__ colba, int nE)
{
    int e = blockIdx.x * 256 + threadIdx.x;
    if (e < nE) {
        int p = atomicAdd(&curab[dab[e]], 1);
        colab[p] = sab[e];
        int q = atomicAdd(&curba[dba[e]], 1);
        colba[q] = sba[e];
    }
}

// ==================== fused attention (gather, online softmax) ====================
__global__ __launch_bounds__(256) void attn_gather(const float* __restrict__ QW,
                                                   const float* __restrict__ K,
                                                   const float* __restrict__ V,
                                                   const int* __restrict__ offs,
                                                   const int* __restrict__ col,
                                                   float* __restrict__ out, int n)
{
    int wid  = (blockIdx.x * 256 + threadIdx.x) >> 6;
    int lane = threadIdx.x & 63;
    if (wid >= n) return;

    int beg = offs[wid], end = offs[wid + 1];
    float2 kv = ((const float2*)(K + (size_t)wid * DD))[lane];

    float m = -__builtin_inff();
    float den = 0.f;
    float2 acc = make_float2(0.f, 0.f);

    for (int p = beg; p < end; ++p) {
        int s = col[p];
        float2 q = ((const float2*)(QW + (size_t)s * DD))[lane];
        float part = q.x * kv.x + q.y * kv.y;
        part += __shfl_xor(part, 1);
        part += __shfl_xor(part, 2);
        part += __shfl_xor(part, 4);
        part += __shfl_xor(part, 8);
        part += __shfl_xor(part, 16);
        part += __shfl_xor(part, 32);
        float sc = part * 0.08838834764831845f;      // 1/sqrt(128)
        sc = sc > 0.f ? sc : 0.01f * sc;             // leaky_relu
        float nm = fmaxf(m, sc);
        float f  = __expf(m - nm);
        float pe = __expf(sc - nm);
        float2 v = ((const float2*)(V + (size_t)s * DD))[lane];
        den   = den * f + pe;
        acc.x = acc.x * f + pe * v.x;
        acc.y = acc.y * f + pe * v.y;
        m = nm;
    }

    float inv = den > 0.f ? 1.f / den : 0.f;
    ((float2*)(out + (size_t)wid * DD))[lane] = make_float2(acc.x * inv, acc.y * inv);
}

// ==================== host ====================
extern "C" void kernel_launch(void* const* d_in, const int* in_sizes, int n_in,
                              void* d_out, int out_size, void* d_ws, size_t ws_size,
                              hipStream_t stream)
{
    const float* x_a    = (const float*)d_in[0];
    const float* x_b    = (const float*)d_in[1];
    const int*   ei_ab  = (const int*)d_in[2];
    const int*   ei_ba  = (const int*)d_in[3];
    const float* qkv_w  = (const float*)d_in[4];
    const float* qkv_b  = (const float*)d_in[5];
    const float* edge_W = (const float*)d_in[6];
    float* out = (float*)d_out;

    const int N = in_sizes[0] / DD;    // 50000
    const int E = in_sizes[2] / 2;     // 600000

    float* ws = (float*)d_ws;
    float* FQ = ws;                        // q  [N*D]
    float* FV = FQ + (size_t)N * DD;       // v  [N*D]
    float* FK = FV + (size_t)N * DD;       // k  [N*D]
    float* HA = FK + (size_t)N * DD;
    float* HB = HA + (size_t)N * DD;
    float* WC  = HB + (size_t)N * DD;      // 4*128*128 f32
    float* BCq = WC + 4 * DD * DD;         // 4*128 f32
    ushort* W3P = (ushort*)(BCq + 4 * DD); // 4*6144*8 bf16
    float* B3  = (float*)(W3P + (size_t)4 * 6144 * 8); // 4*384 f32
    int* ip     = (int*)(B3 + 4 * 384);
    int* deg2   = ip;                          // [2N]
    int* offs2  = deg2 + 2 * (size_t)N;        // [2(N+1)]
    int* col_ab = offs2 + 2 * ((size_t)N + 1); // [E]
    int* col_ba = col_ab + E;                  // [E]

    // ---- weight prep (4 z-combos at once) ----
    {
        dim3 g1(64, 4);
        combine_all<<<g1, 256, 0, stream>>>(qkv_w, qkv_b, edge_W, WC, BCq);
        dim3 g2(24, 4);
        pack_all<<<g2, 256, 0, stream>>>(qkv_w, qkv_b, WC, BCq, W3P, B3);
    }

    // ---- CSR (reused by both layers) ----
    const int* s_ab = ei_ab;  const int* d_ab = ei_ab + E;
    const int* s_ba = ei_ba;  const int* d_ba = ei_ba + E;
    const int e_grid = (E + 255) / 256;
    zero_ints<<<(2 * N + 255) / 256, 256, 0, stream>>>(deg2, 2 * N);
    count_deg<<<e_grid, 256, 0, stream>>>(d_ab, d_ba, deg2, deg2 + N, E);
    scan_deg<<<2, 1024, 0, stream>>>(deg2, offs2, N);
    fill_csr<<<e_grid, 256, 0, stream>>>(s_ab, d_ab, s_ba, d_ba,
                                         deg2, deg2 + N, col_ab, col_ba, E);
    const int* offs_ab = offs2;
    const int* offs_ba = offs2 + (N + 1);

    const dim3 gemm_grid((N + 63) / 64, 3);
    const int ag_grid = (N + 3) / 4;

    auto attend = [&](int z, const float* Xsrc, const float* Xdst, bool relu_in,
                      const int* offs, const int* col, float* outbuf) {
        const ushort* Bp = W3P + (size_t)z * 6144 * 8;
        const float* bz  = B3 + (size_t)z * 384;
        if (relu_in)
            gemm_mfma<true ><<<gemm_grid, 256, 0, stream>>>(Xsrc, Xdst, Bp, bz, FQ, N);
        else
            gemm_mfma<false><<<gemm_grid, 256, 0, stream>>>(Xsrc, Xdst, Bp, bz, FQ, N);
        attn_gather<<<ag_grid, 256, 0, stream>>>(FQ, FK, FV, offs, col, outbuf, N);
    };

    // layer 1
    attend(0, x_a, x_b, false, offs_ab, col_ab, HB);   // a->b, dst b
    attend(1, x_b, x_a, false, offs_ba, col_ba, HA);   // b->a, dst a
    // layer 2 (relu fused into GEMM A-stage)
    float* o_a = out;
    float* o_b = out + (size_t)N * DD;
    attend(2, HA, HB, true, offs_ab, col_ab, o_b);
    attend(3, HB, HA, true, offs_ba, col_ba, o_a);
}

// Round 4
// 681.626 us; speedup vs baseline: 13.7881x; 1.1775x over previous
//
#include <hip/hip_runtime.h>
#include <math.h>

#define DD 128

typedef __attribute__((ext_vector_type(8))) short bf16x8;  // 8 bf16 (4 VGPR)
typedef __attribute__((ext_vector_type(4))) float f32x4;   // 4 fp32 acc

__device__ __forceinline__ ushort f2bf(float f) {
    union { float f; unsigned u; } v; v.f = f;
    unsigned r = v.u + 0x7fff + ((v.u >> 16) & 1);   // RNE
    return (ushort)(r >> 16);
}

// unpack uint (2 packed bf16: low = even elem, high = odd elem) -> 2 floats
__device__ __forceinline__ float2 bfp(unsigned u) {
    union { unsigned x; float f; } a, b;
    a.x = u << 16;
    b.x = u & 0xffff0000u;
    return make_float2(a.f, b.f);
}

// ==================== weight prep (once per launch) ====================
__global__ __launch_bounds__(256) void combine_all(const float* __restrict__ qkv_w,
                                                   const float* __restrict__ qkv_b,
                                                   const float* __restrict__ edge_W,
                                                   float* __restrict__ WC,
                                                   float* __restrict__ BCq)
{
    const int z = blockIdx.y;          // (L<<1)|t
    const int L = z >> 1, t = z & 1;
    const float* wq = qkv_w + (((size_t)L * 2 + t) * 3 + 0) * DD * DD;
    const float* bq = qkv_b + (((size_t)L * 2 + t) * 3 + 0) * DD;
    const float* We = edge_W + ((size_t)L * 2 + t) * DD * DD;
    float* Wz = WC + (size_t)z * DD * DD;
    float* Bz = BCq + (size_t)z * DD;

    const int tid = threadIdx.x;
    const int i = blockIdx.x * 2 + (tid >> 7);
    const int j = tid & 127;
    float sum = 0.f;
    for (int k = 0; k < DD; ++k) sum = fmaf(wq[i * DD + k], We[k * DD + j], sum);
    Wz[i * DD + j] = sum;
    if (blockIdx.x == 0 && tid < DD) {
        float s2 = 0.f;
        for (int k = 0; k < DD; ++k) s2 = fmaf(bq[k], We[k * DD + j], s2);
        Bz[j] = s2;
    }
}

// Pack per z: B-matrix [3 colblocks: q(Wc) | v(wv) | k(wk)] into MFMA-fragment-
// linear bf16 chunks. ci=((cb*8+ct)*4+ks)*64+l ; chunk j: W[k0+j][c3],
// k0=ks*32+(l>>4)*8, c3=cb*128+ct*16+(l&15).  Plus bias3[384].
__global__ __launch_bounds__(256) void pack_all(const float* __restrict__ qkv_w,
                                                const float* __restrict__ qkv_b,
                                                const float* __restrict__ WC,
                                                const float* __restrict__ BCq,
                                                ushort* __restrict__ W3P,
                                                float* __restrict__ B3)
{
    const int z = blockIdx.y;
    const int L = z >> 1, t = z & 1;
    const int ci = blockIdx.x * 256 + threadIdx.x;     // 0..6143
    const int cb = ci >> 11;
    const int ct = (ci >> 8) & 7;
    const int ks = (ci >> 6) & 3;
    const int l  = ci & 63;
    const int c3 = cb * 128 + ct * 16 + (l & 15);
    const int k0 = ks * 32 + (l >> 4) * 8;

    const float* wv = qkv_w + (((size_t)L * 2 + t) * 3 + 2) * DD * DD;
    const float* wk = qkv_w + (((size_t)L * 2 + (t ^ 1)) * 3 + 1) * DD * DD;
    const float* src;
    int cc;
    if (c3 < 128)      { src = WC + (size_t)z * DD * DD; cc = c3; }
    else if (c3 < 256) { src = wv; cc = c3 - 128; }
    else               { src = wk; cc = c3 - 256; }

    ushort h[8];
    #pragma unroll
    for (int j = 0; j < 8; ++j) h[j] = f2bf(src[(size_t)(k0 + j) * DD + cc]);
    ushort* dst = W3P + (size_t)z * 6144 * 8 + (size_t)ci * 8;
    #pragma unroll
    for (int j = 0; j < 8; ++j) dst[j] = h[j];

    if (ci < 384) {
        float bv;
        if (ci < 128)      bv = BCq[(size_t)z * DD + ci];
        else if (ci < 256) bv = qkv_b[(((size_t)L * 2 + t) * 3 + 2) * DD + (ci - 128)];
        else               bv = qkv_b[(((size_t)L * 2 + (t ^ 1)) * 3 + 1) * DD + (ci - 256)];
        B3[(size_t)z * 384 + ci] = bv;
    }
}

// ==================== fused MFMA GEMM (bf16 output) ====================
// grid (ceil(N/64), 3): y=0 -> q=Xsrc@Wc, y=1 -> v=Xsrc@wv, y=2 -> k=Xdst@wk.
template<bool RELU_IN>
__global__ __launch_bounds__(256) void gemm_mfma(const float* __restrict__ Xsrc,
                                                 const float* __restrict__ Xdst,
                                                 const ushort* __restrict__ Bp,   // z-block, 3*16384
                                                 const float* __restrict__ bias,  // [384]
                                                 ushort* __restrict__ outbase,
                                                 int N)
{
    const int by = blockIdx.y;
    const float* X = (by == 2) ? Xdst : Xsrc;
    const ushort* Bz = Bp + (size_t)by * 16384;
    const float* bz = bias + by * 128;
    ushort* out = outbase + (size_t)by * N * DD;

    __shared__ ushort As[1024 * 8];   // 16 KB, frag-linear
    __shared__ ushort Bs[2048 * 8];   // 32 KB, frag-linear

    const int tid  = threadIdx.x;
    const int row0 = blockIdx.x * 64;

    #pragma unroll
    for (int i = 0; i < 8; ++i) {
        int c = tid + i * 256;
        *(float4*)&Bs[(size_t)c * 8] = ((const float4*)Bz)[c];
    }

    {
        const int r = tid >> 2;
        const int q = tid & 3;
        const int grow = row0 + r;
        const bool ok = grow < N;
        const float* xr = X + (size_t)grow * DD;
        #pragma unroll
        for (int i = 0; i < 4; ++i) {
            const int k8 = q + i * 4;        // 0..15
            const int k  = k8 * 8;
            float4 v0 = make_float4(0.f,0.f,0.f,0.f), v1 = v0;
            if (ok) {
                v0 = *(const float4*)&xr[k];
                v1 = *(const float4*)&xr[k + 4];
                if (RELU_IN) {
                    v0.x=fmaxf(v0.x,0.f); v0.y=fmaxf(v0.y,0.f); v0.z=fmaxf(v0.z,0.f); v0.w=fmaxf(v0.w,0.f);
                    v1.x=fmaxf(v1.x,0.f); v1.y=fmaxf(v1.y,0.f); v1.z=fmaxf(v1.z,0.f); v1.w=fmaxf(v1.w,0.f);
                }
            }
            bf16x8 h;
            h[0]=(short)f2bf(v0.x); h[1]=(short)f2bf(v0.y); h[2]=(short)f2bf(v0.z); h[3]=(short)f2bf(v0.w);
            h[4]=(short)f2bf(v1.x); h[5]=(short)f2bf(v1.y); h[6]=(short)f2bf(v1.z); h[7]=(short)f2bf(v1.w);
            const int ks = k >> 5;
            const int l  = (r & 15) + 16 * (k8 & 3);
            const int c  = (r >> 4) * 256 + ks * 64 + l;
            *(bf16x8*)&As[(size_t)c * 8] = h;
        }
    }
    __syncthreads();

    const int wave = tid >> 6;
    const int lane = tid & 63;

    bf16x8 a[4];
    #pragma unroll
    for (int ks = 0; ks < 4; ++ks)
        a[ks] = *(const bf16x8*)&As[(size_t)(wave * 256 + ks * 64 + lane) * 8];

    f32x4 acc[8];
    #pragma unroll
    for (int ct = 0; ct < 8; ++ct) {
        acc[ct] = (f32x4){0.f, 0.f, 0.f, 0.f};
        #pragma unroll
        for (int ks = 0; ks < 4; ++ks) {
            bf16x8 b = *(const bf16x8*)&Bs[(size_t)((ct * 4 + ks) * 64 + lane) * 8];
            acc[ct] = __builtin_amdgcn_mfma_f32_16x16x32_bf16(a[ks], b, acc[ct], 0, 0, 0);
        }
    }

    // store bf16: C/D map col=lane&15, row=(lane>>4)*4+reg
    const int rbase = row0 + wave * 16 + (lane >> 4) * 4;
    #pragma unroll
    for (int ct = 0; ct < 8; ++ct) {
        const int col = ct * 16 + (lane & 15);
        const float bv = bz[col];
        #pragma unroll
        for (int j = 0; j < 4; ++j) {
            const int rr = rbase + j;
            if (rr < N) out[(size_t)rr * DD + col] = f2bf(acc[ct][j] + bv);
        }
    }
}

// ==================== CSR build ====================
__global__ __launch_bounds__(256) void zero_ints(int* __restrict__ p, int n)
{
    int i = blockIdx.x * 256 + threadIdx.x;
    if (i < n) p[i] = 0;
}

__global__ __launch_bounds__(256) void count_deg(const int* __restrict__ dab,
                                                 const int* __restrict__ dba,
                                                 int* __restrict__ degab,
                                                 int* __restrict__ degba, int nE)
{
    int e = blockIdx.x * 256 + threadIdx.x;
    if (e < nE) {
        atomicAdd(&degab[dab[e]], 1);
        atomicAdd(&degba[dba[e]], 1);
    }
}

__global__ __launch_bounds__(1024) void scan_deg(int* __restrict__ deg,
                                                 int* __restrict__ offs, int n)
{
    __shared__ int tmp[1024];
    __shared__ int carry_s;
    int* d = deg + (size_t)blockIdx.x * n;
    int* o = offs + (size_t)blockIdx.x * (n + 1);
    if (threadIdx.x == 0) carry_s = 0;
    __syncthreads();
    for (int base = 0; base < n; base += 1024) {
        int i = base + threadIdx.x;
        int v = (i < n) ? d[i] : 0;
        tmp[threadIdx.x] = v;
        __syncthreads();
        for (int off = 1; off < 1024; off <<= 1) {
            int t = (threadIdx.x >= (unsigned)off) ? tmp[threadIdx.x - off] : 0;
            __syncthreads();
            tmp[threadIdx.x] += t;
            __syncthreads();
        }
        int excl = carry_s + tmp[threadIdx.x] - v;
        if (i < n) { o[i] = excl; d[i] = excl; }
        int total = tmp[1023];
        __syncthreads();
        if (threadIdx.x == 0) carry_s += total;
        __syncthreads();
    }
    if (threadIdx.x == 0) o[n] = carry_s;
}

__global__ __launch_bounds__(256) void fill_csr(const int* __restrict__ sab,
                                                const int* __restrict__ dab,
                                                const int* __restrict__ sba,
                                                const int* __restrict__ dba,
                                                int* __restrict__ curab,
                                                int* __restrict__ curba,
                                                int* __restrict__ colab,
                                                int* __restrict__ colba, int nE)
{
    int e = blockIdx.x * 256 + threadIdx.x;
    if (e < nE) {
        int p = atomicAdd(&curab[dab[e]], 1);
        colab[p] = sab[e];
        int q = atomicAdd(&curba[dba[e]], 1);
        colba[q] = sba[e];
    }
}

// ==================== fused attention (bf16 gather, online softmax) ====================
__global__ __launch_bounds__(256) void attn_gather(const ushort* __restrict__ QW,
                                                   const ushort* __restrict__ K,
                                                   const ushort* __restrict__ V,
                                                   const int* __restrict__ offs,
                                                   const int* __restrict__ col,
                                                   float* __restrict__ out, int n)
{
    int wid  = (blockIdx.x * 256 + threadIdx.x) >> 6;
    int lane = threadIdx.x & 63;
    if (wid >= n) return;

    int beg = offs[wid], end = offs[wid + 1];
    float2 kf = bfp(((const unsigned*)(K + (size_t)wid * DD))[lane]);

    float m = -__builtin_inff();
    float den = 0.f;
    float2 acc = make_float2(0.f, 0.f);

    // 1-deep pipeline: prefetch next edge's q/v rows before current's reduce chain
    unsigned qn = 0, vn = 0;
    if (beg < end) {
        int s0 = col[beg];
        qn = ((const unsigned*)(QW + (size_t)s0 * DD))[lane];
        vn = ((const unsigned*)(V  + (size_t)s0 * DD))[lane];
    }

    for (int p = beg; p < end; ++p) {
        unsigned qu = qn, vu = vn;
        if (p + 1 < end) {
            int s2 = col[p + 1];
            qn = ((const unsigned*)(QW + (size_t)s2 * DD))[lane];
            vn = ((const unsigned*)(V  + (size_t)s2 * DD))[lane];
        }
        float2 qf = bfp(qu);
        float part = qf.x * kf.x + qf.y * kf.y;
        part += __shfl_xor(part, 1);
        part += __shfl_xor(part, 2);
        part += __shfl_xor(part, 4);
        part += __shfl_xor(part, 8);
        part += __shfl_xor(part, 16);
        part += __shfl_xor(part, 32);
        float sc = part * 0.08838834764831845f;      // 1/sqrt(128)
        sc = sc > 0.f ? sc : 0.01f * sc;             // leaky_relu
        float nm = fmaxf(m, sc);
        float f  = __expf(m - nm);
        float pe = __expf(sc - nm);
        float2 vf = bfp(vu);
        den   = den * f + pe;
        acc.x = acc.x * f + pe * vf.x;
        acc.y = acc.y * f + pe * vf.y;
        m = nm;
    }

    float inv = den > 0.f ? 1.f / den : 0.f;
    ((float2*)(out + (size_t)wid * DD))[lane] = make_float2(acc.x * inv, acc.y * inv);
}

// ==================== host ====================
extern "C" void kernel_launch(void* const* d_in, const int* in_sizes, int n_in,
                              void* d_out, int out_size, void* d_ws, size_t ws_size,
                              hipStream_t stream)
{
    const float* x_a    = (const float*)d_in[0];
    const float* x_b    = (const float*)d_in[1];
    const int*   ei_ab  = (const int*)d_in[2];
    const int*   ei_ba  = (const int*)d_in[3];
    const float* qkv_w  = (const float*)d_in[4];
    const float* qkv_b  = (const float*)d_in[5];
    const float* edge_W = (const float*)d_in[6];
    float* out = (float*)d_out;

    const int N = in_sizes[0] / DD;    // 50000
    const int E = in_sizes[2] / 2;     // 600000

    float* ws = (float*)d_ws;
    float* HA = ws;                          // layer-1 out a [N*D] f32
    float* HB = HA + (size_t)N * DD;         // layer-1 out b [N*D] f32
    float* WC  = HB + (size_t)N * DD;        // 4*128*128 f32
    float* BCq = WC + 4 * DD * DD;           // 4*128 f32
    float* B3  = BCq + 4 * DD;               // 4*384 f32
    ushort* W3P = (ushort*)(B3 + 4 * 384);   // 4*6144*8 bf16
    ushort* FQ = W3P + (size_t)4 * 6144 * 8; // q [N*D] bf16
    ushort* FV = FQ + (size_t)N * DD;        // v
    ushort* FK = FV + (size_t)N * DD;        // k
    int* ip     = (int*)(FK + (size_t)N * DD);
    int* deg2   = ip;                          // [2N]
    int* offs2  = deg2 + 2 * (size_t)N;        // [2(N+1)]
    int* col_ab = offs2 + 2 * ((size_t)N + 1); // [E]
    int* col_ba = col_ab + E;                  // [E]

    // ---- weight prep ----
    {
        dim3 g1(64, 4);
        combine_all<<<g1, 256, 0, stream>>>(qkv_w, qkv_b, edge_W, WC, BCq);
        dim3 g2(24, 4);
        pack_all<<<g2, 256, 0, stream>>>(qkv_w, qkv_b, WC, BCq, W3P, B3);
    }

    // ---- CSR (reused by both layers) ----
    const int* s_ab = ei_ab;  const int* d_ab = ei_ab + E;
    const int* s_ba = ei_ba;  const int* d_ba = ei_ba + E;
    const int e_grid = (E + 255) / 256;
    zero_ints<<<(2 * N + 255) / 256, 256, 0, stream>>>(deg2, 2 * N);
    count_deg<<<e_grid, 256, 0, stream>>>(d_ab, d_ba, deg2, deg2 + N, E);
    scan_deg<<<2, 1024, 0, stream>>>(deg2, offs2, N);
    fill_csr<<<e_grid, 256, 0, stream>>>(s_ab, d_ab, s_ba, d_ba,
                                         deg2, deg2 + N, col_ab, col_ba, E);
    const int* offs_ab = offs2;
    const int* offs_ba = offs2 + (N + 1);

    const dim3 gemm_grid((N + 63) / 64, 3);
    const int ag_grid = (N + 3) / 4;

    auto attend = [&](int z, const float* Xsrc, const float* Xdst, bool relu_in,
                      const int* offs, const int* col, float* outbuf) {
        const ushort* Bp = W3P + (size_t)z * 6144 * 8;
        const float* bz  = B3 + (size_t)z * 384;
        if (relu_in)
            gemm_mfma<true ><<<gemm_grid, 256, 0, stream>>>(Xsrc, Xdst, Bp, bz, FQ, N);
        else
            gemm_mfma<false><<<gemm_grid, 256, 0, stream>>>(Xsrc, Xdst, Bp, bz, FQ, N);
        attn_gather<<<ag_grid, 256, 0, stream>>>(FQ, FK, FV, offs, col, outbuf, N);
    };

    // layer 1
    attend(0, x_a, x_b, false, offs_ab, col_ab, HB);   // a->b, dst b
    attend(1, x_b, x_a, false, offs_ba, col_ba, HA);   // b->a, dst a
    // layer 2 (relu fused into GEMM A-stage)
    float* o_a = out;
    float* o_b = out + (size_t)N * DD;
    attend(2, HA, HB, true, offs_ab, col_ab, o_b);
    attend(3, HB, HA, true, offs_ba, col_ba, o_a);
}